// Round 1
// baseline (469.958 us; speedup 1.0000x reference)
//
#include <hip/hip_runtime.h>
#include <math.h>

#define N_NODES 50000
#define N_EDGES 800000
#define EP (N_EDGES + N_NODES)   // 850000 edges incl. self loops
#define NEG 0.2f
#define SCAN_BLOCKS 49           // ceil(50000/1024)

// ---------------- CSR build ----------------

__global__ void k_hist(const int* __restrict__ ei, int* __restrict__ counts) {
    int e = blockIdx.x * 256 + threadIdx.x;
    if (e >= EP) return;
    int d = (e < N_EDGES) ? ei[N_EDGES + e] : (e - N_EDGES);
    atomicAdd(&counts[d], 1);
}

// block = 256 threads, each thread 4 elements, block chunk = 1024
__global__ void k_scan_block(const int* __restrict__ counts, int* __restrict__ excl,
                             int* __restrict__ bsums) {
    __shared__ int wsum[4];
    int b = blockIdx.x, t = threadIdx.x;
    int lane = t & 63, w = t >> 6;
    int i0 = b * 1024 + t * 4;
    int v0 = (i0 + 0 < N_NODES) ? counts[i0 + 0] : 0;
    int v1 = (i0 + 1 < N_NODES) ? counts[i0 + 1] : 0;
    int v2 = (i0 + 2 < N_NODES) ? counts[i0 + 2] : 0;
    int v3 = (i0 + 3 < N_NODES) ? counts[i0 + 3] : 0;
    int s = v0 + v1 + v2 + v3;
    int incl = s;
    #pragma unroll
    for (int d = 1; d < 64; d <<= 1) {
        int u = __shfl_up(incl, d);
        if (lane >= d) incl += u;
    }
    if (lane == 63) wsum[w] = incl;
    __syncthreads();
    if (t == 0) {
        int run = 0;
        #pragma unroll
        for (int i = 0; i < 4; ++i) { int x = wsum[i]; wsum[i] = run; run += x; }
        bsums[b] = run;   // block total
    }
    __syncthreads();
    int base = wsum[w] + incl - s;   // exclusive prefix of this thread's chunk
    if (i0 + 0 < N_NODES) excl[i0 + 0] = base;
    if (i0 + 1 < N_NODES) excl[i0 + 1] = base + v0;
    if (i0 + 2 < N_NODES) excl[i0 + 2] = base + v0 + v1;
    if (i0 + 3 < N_NODES) excl[i0 + 3] = base + v0 + v1 + v2;
}

__global__ void k_scan_mid(int* __restrict__ bsums) {
    int t = threadIdx.x;  // 64 threads, SCAN_BLOCKS <= 64
    int v = (t < SCAN_BLOCKS) ? bsums[t] : 0;
    int incl = v;
    #pragma unroll
    for (int d = 1; d < 64; d <<= 1) {
        int u = __shfl_up(incl, d);
        if (t >= d) incl += u;
    }
    if (t < SCAN_BLOCKS) bsums[t] = incl - v;  // exclusive
}

__global__ void k_scan_add(int* __restrict__ row_ptr, const int* __restrict__ bsums) {
    int b = blockIdx.x, t = threadIdx.x;
    int off = bsums[b];
    int i0 = b * 1024 + t * 4;
    #pragma unroll
    for (int j = 0; j < 4; ++j)
        if (i0 + j < N_NODES) row_ptr[i0 + j] += off;
    if (b == 0 && t == 0) row_ptr[N_NODES] = EP;
}

__global__ void k_scatter(const int* __restrict__ ei, const int* __restrict__ row_ptr,
                          int* __restrict__ fill, int* __restrict__ colb) {
    int e = blockIdx.x * 256 + threadIdx.x;
    if (e >= EP) return;
    int s, d;
    if (e < N_EDGES) { s = ei[e]; d = ei[N_EDGES + e]; }
    else             { s = e - N_EDGES; d = s; }
    int pos = row_ptr[d] + atomicAdd(&fill[d], 1);
    colb[pos] = s;
}

// ---------------- Layer 1 GEMM: xp1 = x @ W1 (50000x256 @ 256x256) ----------------
// block = 256 threads = 16 rows x 256 cols tile; x rows staged in LDS,
// W1 columns streamed (L2-resident, 256 KB total).
__global__ void k_gemm1(const float* __restrict__ x, const float* __restrict__ W1,
                        float* __restrict__ xp1) {
    __shared__ float xs[16 * 256];
    int t = threadIdx.x;
    int row0 = blockIdx.x * 16;     // 3125 * 16 == 50000 exactly
    #pragma unroll
    for (int i = 0; i < 16; ++i)
        xs[i * 256 + t] = x[(row0 + i) * 256 + t];
    __syncthreads();
    const float4* xs4 = (const float4*)xs;
    int col = t;
    float acc[16];
    #pragma unroll
    for (int r = 0; r < 16; ++r) acc[r] = 0.f;
    for (int k4 = 0; k4 < 64; ++k4) {
        int k = k4 * 4;
        float w0 = W1[(k + 0) * 256 + col];
        float w1 = W1[(k + 1) * 256 + col];
        float w2 = W1[(k + 2) * 256 + col];
        float w3 = W1[(k + 3) * 256 + col];
        #pragma unroll
        for (int r = 0; r < 16; ++r) {
            float4 xv = xs4[r * 64 + k4];
            acc[r] = fmaf(xv.x, w0, acc[r]);
            acc[r] = fmaf(xv.y, w1, acc[r]);
            acc[r] = fmaf(xv.z, w2, acc[r]);
            acc[r] = fmaf(xv.w, w3, acc[r]);
        }
    }
    #pragma unroll
    for (int r = 0; r < 16; ++r)
        xp1[(row0 + r) * 256 + col] = acc[r];
}

// ---------------- per-node attention logits, layer 1 ----------------
// wave per node; lane l covers channels [4l,4l+3], head = l>>3
__global__ void k_alphas1(const float* __restrict__ xp, const float* __restrict__ asrc,
                          const float* __restrict__ adst,
                          float* __restrict__ as1, float* __restrict__ ad1) {
    int t = threadIdx.x, l = t & 63, w = t >> 6;
    int n = blockIdx.x * 4 + w;
    float4 xv = ((const float4*)xp)[n * 64 + l];
    float4 a_s = ((const float4*)asrc)[l];
    float4 a_d = ((const float4*)adst)[l];
    float ds = xv.x * a_s.x + xv.y * a_s.y + xv.z * a_s.z + xv.w * a_s.w;
    float dd = xv.x * a_d.x + xv.y * a_d.y + xv.z * a_d.z + xv.w * a_d.w;
    #pragma unroll
    for (int m = 1; m < 8; m <<= 1) {
        ds += __shfl_xor(ds, m);
        dd += __shfl_xor(dd, m);
    }
    if ((l & 7) == 0) {
        int h = l >> 3;
        as1[n * 8 + h] = ds;
        ad1[n * 8 + h] = dd;
    }
}

// ---------------- fused segment-softmax + aggregate, layer 1 ----------------
// softmax(e) aggregation == (sum p_i * x_i) / (sum p_i); max-subtraction not
// needed (|e| <~ 5, exp safe in fp32). One wave per node; per-edge 1KB
// coalesced gather of xp[src] (xp1 is 51 MB -> Infinity-Cache resident).
__global__ void k_agg1(const float* __restrict__ xp, const float* __restrict__ as1,
                       const float* __restrict__ ad1, const int* __restrict__ row_ptr,
                       const int* __restrict__ colb, const float* __restrict__ b1,
                       float* __restrict__ hout) {
    int t = threadIdx.x, l = t & 63, w = t >> 6;
    int n = blockIdx.x * 4 + w;
    int hidx = l >> 3;
    float adn = ad1[n * 8 + hidx];
    int start = row_ptr[n], end = row_ptr[n + 1];
    float4 acc = {0.f, 0.f, 0.f, 0.f};
    float den = 0.f;
    for (int j = start; j < end; ++j) {
        int s = colb[j];
        float e = as1[s * 8 + hidx] + adn;
        e = (e > 0.f) ? e : NEG * e;
        float p = __expf(e);
        den += p;
        float4 xv = ((const float4*)xp)[s * 64 + l];
        acc.x = fmaf(p, xv.x, acc.x);
        acc.y = fmaf(p, xv.y, acc.y);
        acc.z = fmaf(p, xv.z, acc.z);
        acc.w = fmaf(p, xv.w, acc.w);
    }
    float4 bv = ((const float4*)b1)[l];
    float inv = 1.f / den;
    float4 o;
    o.x = fmaxf(acc.x * inv + bv.x, 0.f);
    o.y = fmaxf(acc.y * inv + bv.y, 0.f);
    o.z = fmaxf(acc.z * inv + bv.z, 0.f);
    o.w = fmaxf(acc.w * inv + bv.w, 0.f);
    ((float4*)hout)[n * 64 + l] = o;
}

// ---------------- layer 2 projection + logits: xp2 = h @ W2 (256->2) ----------------
// wave per node; W2 row-major (256,2): lane l needs W2[8l..8l+7]
__global__ void k_proj2(const float* __restrict__ h, const float* __restrict__ W2,
                        const float* __restrict__ as2w, const float* __restrict__ ad2w,
                        float* __restrict__ xp2, float* __restrict__ as2,
                        float* __restrict__ ad2) {
    int t = threadIdx.x, l = t & 63, w = t >> 6;
    int n = blockIdx.x * 4 + w;
    float4 hv = ((const float4*)h)[n * 64 + l];
    float4 wa = ((const float4*)W2)[2 * l];
    float4 wb = ((const float4*)W2)[2 * l + 1];
    float d0 = hv.x * wa.x + hv.y * wa.z + hv.z * wb.x + hv.w * wb.z;
    float d1 = hv.x * wa.y + hv.y * wa.w + hv.z * wb.y + hv.w * wb.w;
    #pragma unroll
    for (int m = 1; m < 64; m <<= 1) {
        d0 += __shfl_xor(d0, m);
        d1 += __shfl_xor(d1, m);
    }
    if (l == 0) {
        xp2[2 * n] = d0;
        xp2[2 * n + 1] = d1;
        as2[n] = d0 * as2w[0] + d1 * as2w[1];
        ad2[n] = d0 * ad2w[0] + d1 * ad2w[1];
    }
}

// ---------------- fused segment-softmax + aggregate, layer 2 (2 channels) ----------------
// wave per node, lanes parallel over incident edges
__global__ void k_agg2(const float* __restrict__ xp2, const float* __restrict__ as2,
                       const float* __restrict__ ad2, const int* __restrict__ row_ptr,
                       const int* __restrict__ colb, const float* __restrict__ b2,
                       float* __restrict__ out) {
    int t = threadIdx.x, l = t & 63, w = t >> 6;
    int n = blockIdx.x * 4 + w;
    int start = row_ptr[n], end = row_ptr[n + 1];
    float adn = ad2[n];
    float a0 = 0.f, a1 = 0.f, den = 0.f;
    for (int j = start + l; j < end; j += 64) {
        int s = colb[j];
        float e = as2[s] + adn;
        e = (e > 0.f) ? e : NEG * e;
        float p = __expf(e);
        den += p;
        a0 = fmaf(p, xp2[2 * s], a0);
        a1 = fmaf(p, xp2[2 * s + 1], a1);
    }
    #pragma unroll
    for (int m = 1; m < 64; m <<= 1) {
        a0 += __shfl_xor(a0, m);
        a1 += __shfl_xor(a1, m);
        den += __shfl_xor(den, m);
    }
    if (l == 0) {
        out[2 * n] = a0 / den + b2[0];
        out[2 * n + 1] = a1 / den + b2[1];
    }
}

extern "C" void kernel_launch(void* const* d_in, const int* in_sizes, int n_in,
                              void* d_out, int out_size, void* d_ws, size_t ws_size,
                              hipStream_t stream) {
    const float* x     = (const float*)d_in[0];
    const int*   ei    = (const int*)d_in[1];
    const float* W1    = (const float*)d_in[2];
    const float* asrc1 = (const float*)d_in[3];
    const float* adst1 = (const float*)d_in[4];
    const float* b1    = (const float*)d_in[5];
    const float* W2    = (const float*)d_in[6];
    const float* asrc2 = (const float*)d_in[7];
    const float* adst2 = (const float*)d_in[8];
    const float* b2    = (const float*)d_in[9];
    float* out = (float*)d_out;

    char* ws = (char*)d_ws;
    float* xp1     = (float*)(ws + 0);              // 51,200,000 B
    float* hbuf    = (float*)(ws + 51200000);       // 51,200,000 B
    float* as1     = (float*)(ws + 102400000);      //  1,600,000 B
    float* ad1     = (float*)(ws + 104000000);      //  1,600,000 B
    float* xp2     = (float*)(ws + 105600000);      //    400,000 B
    float* as2     = (float*)(ws + 106000000);      //    200,000 B
    float* ad2     = (float*)(ws + 106200000);      //    200,000 B
    int*   counts  = (int*)  (ws + 106400000);      //    200,000 B
    int*   fill    = (int*)  (ws + 106600000);      //    200,000 B (contig w/ counts)
    int*   row_ptr = (int*)  (ws + 106800000);      //    200,064 B
    int*   colb    = (int*)  (ws + 107000064);      //  3,400,000 B
    int*   bsums   = (int*)  (ws + 110400064);      //        256 B

    // zero counts + fill in one memset (contiguous)
    hipMemsetAsync(counts, 0, 400000, stream);

    int egrid = (EP + 255) / 256;
    k_hist      <<<egrid,       256, 0, stream>>>(ei, counts);
    k_scan_block<<<SCAN_BLOCKS, 256, 0, stream>>>(counts, row_ptr, bsums);
    k_scan_mid  <<<1,            64, 0, stream>>>(bsums);
    k_scan_add  <<<SCAN_BLOCKS, 256, 0, stream>>>(row_ptr, bsums);
    k_scatter   <<<egrid,       256, 0, stream>>>(ei, row_ptr, fill, colb);

    k_gemm1     <<<3125,  256, 0, stream>>>(x, W1, xp1);
    k_alphas1   <<<12500, 256, 0, stream>>>(xp1, asrc1, adst1, as1, ad1);
    k_agg1      <<<12500, 256, 0, stream>>>(xp1, as1, ad1, row_ptr, colb, b1, hbuf);
    k_proj2     <<<12500, 256, 0, stream>>>(hbuf, W2, asrc2, adst2, xp2, as2, ad2);
    k_agg2      <<<12500, 256, 0, stream>>>(xp2, as2, ad2, row_ptr, colb, b2, out);
}

// Round 2
// 440.208 us; speedup vs baseline: 1.0676x; 1.0676x over previous
//
#include <hip/hip_runtime.h>
#include <math.h>

#define N_NODES 50000
#define N_EDGES 800000
#define EP (N_EDGES + N_NODES)   // 850000 edges incl. self loops
#define NEG 0.2f
#define SCAN_BLOCKS 49           // ceil(50000/1024)

// ---------------- CSR build ----------------

__global__ void k_hist(const int* __restrict__ ei, int* __restrict__ counts) {
    int e = blockIdx.x * 256 + threadIdx.x;
    if (e >= EP) return;
    int d = (e < N_EDGES) ? ei[N_EDGES + e] : (e - N_EDGES);
    atomicAdd(&counts[d], 1);
}

// block = 256 threads, each thread 4 elements, block chunk = 1024
__global__ void k_scan_block(const int* __restrict__ counts, int* __restrict__ excl,
                             int* __restrict__ bsums) {
    __shared__ int wsum[4];
    int b = blockIdx.x, t = threadIdx.x;
    int lane = t & 63, w = t >> 6;
    int i0 = b * 1024 + t * 4;
    int v0 = (i0 + 0 < N_NODES) ? counts[i0 + 0] : 0;
    int v1 = (i0 + 1 < N_NODES) ? counts[i0 + 1] : 0;
    int v2 = (i0 + 2 < N_NODES) ? counts[i0 + 2] : 0;
    int v3 = (i0 + 3 < N_NODES) ? counts[i0 + 3] : 0;
    int s = v0 + v1 + v2 + v3;
    int incl = s;
    #pragma unroll
    for (int d = 1; d < 64; d <<= 1) {
        int u = __shfl_up(incl, d);
        if (lane >= d) incl += u;
    }
    if (lane == 63) wsum[w] = incl;
    __syncthreads();
    if (t == 0) {
        int run = 0;
        #pragma unroll
        for (int i = 0; i < 4; ++i) { int x = wsum[i]; wsum[i] = run; run += x; }
        bsums[b] = run;   // block total
    }
    __syncthreads();
    int base = wsum[w] + incl - s;   // exclusive prefix of this thread's chunk
    if (i0 + 0 < N_NODES) excl[i0 + 0] = base;
    if (i0 + 1 < N_NODES) excl[i0 + 1] = base + v0;
    if (i0 + 2 < N_NODES) excl[i0 + 2] = base + v0 + v1;
    if (i0 + 3 < N_NODES) excl[i0 + 3] = base + v0 + v1 + v2;
}

__global__ void k_scan_mid(int* __restrict__ bsums) {
    int t = threadIdx.x;  // 64 threads, SCAN_BLOCKS <= 64
    int v = (t < SCAN_BLOCKS) ? bsums[t] : 0;
    int incl = v;
    #pragma unroll
    for (int d = 1; d < 64; d <<= 1) {
        int u = __shfl_up(incl, d);
        if (t >= d) incl += u;
    }
    if (t < SCAN_BLOCKS) bsums[t] = incl - v;  // exclusive
}

__global__ void k_scan_add(int* __restrict__ row_ptr, const int* __restrict__ bsums) {
    int b = blockIdx.x, t = threadIdx.x;
    int off = bsums[b];
    int i0 = b * 1024 + t * 4;
    #pragma unroll
    for (int j = 0; j < 4; ++j)
        if (i0 + j < N_NODES) row_ptr[i0 + j] += off;
    if (b == 0 && t == 0) row_ptr[N_NODES] = EP;
}

__global__ void k_scatter(const int* __restrict__ ei, const int* __restrict__ row_ptr,
                          int* __restrict__ fill, int* __restrict__ colb) {
    int e = blockIdx.x * 256 + threadIdx.x;
    if (e >= EP) return;
    int s, d;
    if (e < N_EDGES) { s = ei[e]; d = ei[N_EDGES + e]; }
    else             { s = e - N_EDGES; d = s; }
    int pos = row_ptr[d] + atomicAdd(&fill[d], 1);
    colb[pos] = s;
}

// ---------------- Layer 1 GEMM: xp1 = x @ W1 (50000x256 @ 256x256) ----------------
// v2: FMA-density restructure. Block = 32 rows x 256 cols, 256 threads (4 waves).
// Wave w owns rows w*8..w*8+7; lane l owns cols 4l..4l+3 (acc = 8 x float4).
// A-tile in LDS (32 KB); A reads are wave-uniform ds_read_b128 broadcasts
// (conflict-free, imm-offset addressing). W rows stream from L1/L2 as
// coalesced dwordx4 (256 KB total, all waves share). Per k4-step/lane:
// 128 FMA (256 VALU cyc) vs 8 ds_read_b128 (~96 cyc) + 4 vmem -> VALU-bound.
#define G1_ROWS 32
#define G1_GRID 1563            // ceil(50000/32); last block has 16 valid rows
__global__ void k_gemm1(const float* __restrict__ x, const float* __restrict__ W1,
                        float* __restrict__ xp1) {
    __shared__ float xs[G1_ROWS * 256];
    int t = threadIdx.x;
    int row0 = blockIdx.x * G1_ROWS;

    // stage A-tile: 32x256 floats = 2048 float4, 8 per thread, linear copy
    const float4* x4 = (const float4*)x;
    float4* xs4w = (float4*)xs;
    #pragma unroll
    for (int c = 0; c < 8; ++c) {
        int idx = c * 256 + t;            // float4 index within tile
        int r = idx >> 6, c4 = idx & 63;
        int gr = row0 + r;
        if (gr > N_NODES - 1) gr = N_NODES - 1;   // clamp (results unused)
        xs4w[idx] = x4[gr * 64 + c4];
    }
    __syncthreads();

    int l = t & 63, w = t >> 6;
    int r0 = w * 8;                       // this wave's first row in tile
    const float4* xs4 = (const float4*)xs;
    const float4* W4 = (const float4*)W1; // W1[k][c]: float4 index k*64 + (c/4)

    float4 acc[8];
    #pragma unroll
    for (int r = 0; r < 8; ++r) acc[r] = make_float4(0.f, 0.f, 0.f, 0.f);

    #pragma unroll 4
    for (int k4 = 0; k4 < 64; ++k4) {
        float4 wv0 = W4[(k4 * 4 + 0) * 64 + l];
        float4 wv1 = W4[(k4 * 4 + 1) * 64 + l];
        float4 wv2 = W4[(k4 * 4 + 2) * 64 + l];
        float4 wv3 = W4[(k4 * 4 + 3) * 64 + l];
        #pragma unroll
        for (int r = 0; r < 8; ++r) {
            float4 av = xs4[(r0 + r) * 64 + k4];   // wave-uniform broadcast
            acc[r].x = fmaf(av.x, wv0.x, acc[r].x);
            acc[r].x = fmaf(av.y, wv1.x, acc[r].x);
            acc[r].x = fmaf(av.z, wv2.x, acc[r].x);
            acc[r].x = fmaf(av.w, wv3.x, acc[r].x);
            acc[r].y = fmaf(av.x, wv0.y, acc[r].y);
            acc[r].y = fmaf(av.y, wv1.y, acc[r].y);
            acc[r].y = fmaf(av.z, wv2.y, acc[r].y);
            acc[r].y = fmaf(av.w, wv3.y, acc[r].y);
            acc[r].z = fmaf(av.x, wv0.z, acc[r].z);
            acc[r].z = fmaf(av.y, wv1.z, acc[r].z);
            acc[r].z = fmaf(av.z, wv2.z, acc[r].z);
            acc[r].z = fmaf(av.w, wv3.z, acc[r].z);
            acc[r].w = fmaf(av.x, wv0.w, acc[r].w);
            acc[r].w = fmaf(av.y, wv1.w, acc[r].w);
            acc[r].w = fmaf(av.z, wv2.w, acc[r].w);
            acc[r].w = fmaf(av.w, wv3.w, acc[r].w);
        }
    }

    float4* o4 = (float4*)xp1;
    #pragma unroll
    for (int r = 0; r < 8; ++r) {
        int gr = row0 + r0 + r;
        if (gr < N_NODES) o4[gr * 64 + l] = acc[r];
    }
}

// ---------------- per-node attention logits, layer 1 ----------------
// wave per node; lane l covers channels [4l,4l+3], head = l>>3
__global__ void k_alphas1(const float* __restrict__ xp, const float* __restrict__ asrc,
                          const float* __restrict__ adst,
                          float* __restrict__ as1, float* __restrict__ ad1) {
    int t = threadIdx.x, l = t & 63, w = t >> 6;
    int n = blockIdx.x * 4 + w;
    float4 xv = ((const float4*)xp)[n * 64 + l];
    float4 a_s = ((const float4*)asrc)[l];
    float4 a_d = ((const float4*)adst)[l];
    float ds = xv.x * a_s.x + xv.y * a_s.y + xv.z * a_s.z + xv.w * a_s.w;
    float dd = xv.x * a_d.x + xv.y * a_d.y + xv.z * a_d.z + xv.w * a_d.w;
    #pragma unroll
    for (int m = 1; m < 8; m <<= 1) {
        ds += __shfl_xor(ds, m);
        dd += __shfl_xor(dd, m);
    }
    if ((l & 7) == 0) {
        int h = l >> 3;
        as1[n * 8 + h] = ds;
        ad1[n * 8 + h] = dd;
    }
}

// ---------------- fused segment-softmax + aggregate, layer 1 ----------------
// softmax(e) aggregation == (sum p_i * x_i) / (sum p_i); max-subtraction not
// needed (|e| <~ 5, exp safe in fp32). One wave per node; per-edge 1KB
// coalesced gather of xp[src] (xp1 is 51 MB -> Infinity-Cache resident).
__global__ void k_agg1(const float* __restrict__ xp, const float* __restrict__ as1,
                       const float* __restrict__ ad1, const int* __restrict__ row_ptr,
                       const int* __restrict__ colb, const float* __restrict__ b1,
                       float* __restrict__ hout) {
    int t = threadIdx.x, l = t & 63, w = t >> 6;
    int n = blockIdx.x * 4 + w;
    int hidx = l >> 3;
    float adn = ad1[n * 8 + hidx];
    int start = row_ptr[n], end = row_ptr[n + 1];
    float4 acc = {0.f, 0.f, 0.f, 0.f};
    float den = 0.f;
    for (int j = start; j < end; ++j) {
        int s = colb[j];
        float e = as1[s * 8 + hidx] + adn;
        e = (e > 0.f) ? e : NEG * e;
        float p = __expf(e);
        den += p;
        float4 xv = ((const float4*)xp)[s * 64 + l];
        acc.x = fmaf(p, xv.x, acc.x);
        acc.y = fmaf(p, xv.y, acc.y);
        acc.z = fmaf(p, xv.z, acc.z);
        acc.w = fmaf(p, xv.w, acc.w);
    }
    float4 bv = ((const float4*)b1)[l];
    float inv = 1.f / den;
    float4 o;
    o.x = fmaxf(acc.x * inv + bv.x, 0.f);
    o.y = fmaxf(acc.y * inv + bv.y, 0.f);
    o.z = fmaxf(acc.z * inv + bv.z, 0.f);
    o.w = fmaxf(acc.w * inv + bv.w, 0.f);
    ((float4*)hout)[n * 64 + l] = o;
}

// ---------------- layer 2 projection + logits: xp2 = h @ W2 (256->2) ----------------
// wave per node; W2 row-major (256,2): lane l needs W2[8l..8l+7]
__global__ void k_proj2(const float* __restrict__ h, const float* __restrict__ W2,
                        const float* __restrict__ as2w, const float* __restrict__ ad2w,
                        float* __restrict__ xp2, float* __restrict__ as2,
                        float* __restrict__ ad2) {
    int t = threadIdx.x, l = t & 63, w = t >> 6;
    int n = blockIdx.x * 4 + w;
    float4 hv = ((const float4*)h)[n * 64 + l];
    float4 wa = ((const float4*)W2)[2 * l];
    float4 wb = ((const float4*)W2)[2 * l + 1];
    float d0 = hv.x * wa.x + hv.y * wa.z + hv.z * wb.x + hv.w * wb.z;
    float d1 = hv.x * wa.y + hv.y * wa.w + hv.z * wb.y + hv.w * wb.w;
    #pragma unroll
    for (int m = 1; m < 64; m <<= 1) {
        d0 += __shfl_xor(d0, m);
        d1 += __shfl_xor(d1, m);
    }
    if (l == 0) {
        xp2[2 * n] = d0;
        xp2[2 * n + 1] = d1;
        as2[n] = d0 * as2w[0] + d1 * as2w[1];
        ad2[n] = d0 * ad2w[0] + d1 * ad2w[1];
    }
}

// ---------------- fused segment-softmax + aggregate, layer 2 (2 channels) ----------------
// wave per node, lanes parallel over incident edges
__global__ void k_agg2(const float* __restrict__ xp2, const float* __restrict__ as2,
                       const float* __restrict__ ad2, const int* __restrict__ row_ptr,
                       const int* __restrict__ colb, const float* __restrict__ b2,
                       float* __restrict__ out) {
    int t = threadIdx.x, l = t & 63, w = t >> 6;
    int n = blockIdx.x * 4 + w;
    int start = row_ptr[n], end = row_ptr[n + 1];
    float adn = ad2[n];
    float a0 = 0.f, a1 = 0.f, den = 0.f;
    for (int j = start + l; j < end; j += 64) {
        int s = colb[j];
        float e = as2[s] + adn;
        e = (e > 0.f) ? e : NEG * e;
        float p = __expf(e);
        den += p;
        a0 = fmaf(p, xp2[2 * s], a0);
        a1 = fmaf(p, xp2[2 * s + 1], a1);
    }
    #pragma unroll
    for (int m = 1; m < 64; m <<= 1) {
        a0 += __shfl_xor(a0, m);
        a1 += __shfl_xor(a1, m);
        den += __shfl_xor(den, m);
    }
    if (l == 0) {
        out[2 * n] = a0 / den + b2[0];
        out[2 * n + 1] = a1 / den + b2[1];
    }
}

extern "C" void kernel_launch(void* const* d_in, const int* in_sizes, int n_in,
                              void* d_out, int out_size, void* d_ws, size_t ws_size,
                              hipStream_t stream) {
    const float* x     = (const float*)d_in[0];
    const int*   ei    = (const int*)d_in[1];
    const float* W1    = (const float*)d_in[2];
    const float* asrc1 = (const float*)d_in[3];
    const float* adst1 = (const float*)d_in[4];
    const float* b1    = (const float*)d_in[5];
    const float* W2    = (const float*)d_in[6];
    const float* asrc2 = (const float*)d_in[7];
    const float* adst2 = (const float*)d_in[8];
    const float* b2    = (const float*)d_in[9];
    float* out = (float*)d_out;

    char* ws = (char*)d_ws;
    float* xp1     = (float*)(ws + 0);              // 51,200,000 B
    float* hbuf    = (float*)(ws + 51200000);       // 51,200,000 B
    float* as1     = (float*)(ws + 102400000);      //  1,600,000 B
    float* ad1     = (float*)(ws + 104000000);      //  1,600,000 B
    float* xp2     = (float*)(ws + 105600000);      //    400,000 B
    float* as2     = (float*)(ws + 106000000);      //    200,000 B
    float* ad2     = (float*)(ws + 106200000);      //    200,000 B
    int*   counts  = (int*)  (ws + 106400000);      //    200,000 B
    int*   fill    = (int*)  (ws + 106600000);      //    200,000 B (contig w/ counts)
    int*   row_ptr = (int*)  (ws + 106800000);      //    200,064 B
    int*   colb    = (int*)  (ws + 107000064);      //  3,400,000 B
    int*   bsums   = (int*)  (ws + 110400064);      //        256 B

    // zero counts + fill in one memset (contiguous)
    hipMemsetAsync(counts, 0, 400000, stream);

    int egrid = (EP + 255) / 256;
    k_hist      <<<egrid,       256, 0, stream>>>(ei, counts);
    k_scan_block<<<SCAN_BLOCKS, 256, 0, stream>>>(counts, row_ptr, bsums);
    k_scan_mid  <<<1,            64, 0, stream>>>(bsums);
    k_scan_add  <<<SCAN_BLOCKS, 256, 0, stream>>>(row_ptr, bsums);
    k_scatter   <<<egrid,       256, 0, stream>>>(ei, row_ptr, fill, colb);

    k_gemm1     <<<G1_GRID, 256, 0, stream>>>(x, W1, xp1);
    k_alphas1   <<<12500,  256, 0, stream>>>(xp1, asrc1, adst1, as1, ad1);
    k_agg1      <<<12500,  256, 0, stream>>>(xp1, as1, ad1, row_ptr, colb, b1, hbuf);
    k_proj2     <<<12500,  256, 0, stream>>>(hbuf, W2, asrc2, adst2, xp2, as2, ad2);
    k_agg2      <<<12500,  256, 0, stream>>>(xp2, as2, ad2, row_ptr, colb, b2, out);
}

// Round 3
// 365.882 us; speedup vs baseline: 1.2845x; 1.2031x over previous
//
#include <hip/hip_runtime.h>
#include <math.h>

#define N_NODES 50000
#define N_EDGES 800000
#define EP (N_EDGES + N_NODES)   // 850000 edges incl. self loops
#define NEG 0.2f
#define SCAN_BLOCKS 49           // ceil(50000/1024)

// bf16 round-to-nearest-even from fp32
static __device__ __forceinline__ unsigned short bf16_rn(float f) {
    union { float f; unsigned int u; } v; v.f = f;
    unsigned int u = v.u;
    unsigned int r = (u + 0x7FFFu + ((u >> 16) & 1u)) >> 16;
    return (unsigned short)r;
}
static __device__ __forceinline__ float bf16_tof(unsigned short u) {
    union { unsigned int u; float f; } v; v.u = ((unsigned int)u) << 16;
    return v.f;
}

// ---------------- CSR build ----------------

__global__ void k_hist(const int* __restrict__ ei, int* __restrict__ counts) {
    int e = blockIdx.x * 256 + threadIdx.x;
    if (e >= EP) return;
    int d = (e < N_EDGES) ? ei[N_EDGES + e] : (e - N_EDGES);
    atomicAdd(&counts[d], 1);
}

// block = 256 threads, each thread 4 elements, block chunk = 1024
__global__ void k_scan_block(const int* __restrict__ counts, int* __restrict__ excl,
                             int* __restrict__ bsums) {
    __shared__ int wsum[4];
    int b = blockIdx.x, t = threadIdx.x;
    int lane = t & 63, w = t >> 6;
    int i0 = b * 1024 + t * 4;
    int v0 = (i0 + 0 < N_NODES) ? counts[i0 + 0] : 0;
    int v1 = (i0 + 1 < N_NODES) ? counts[i0 + 1] : 0;
    int v2 = (i0 + 2 < N_NODES) ? counts[i0 + 2] : 0;
    int v3 = (i0 + 3 < N_NODES) ? counts[i0 + 3] : 0;
    int s = v0 + v1 + v2 + v3;
    int incl = s;
    #pragma unroll
    for (int d = 1; d < 64; d <<= 1) {
        int u = __shfl_up(incl, d);
        if (lane >= d) incl += u;
    }
    if (lane == 63) wsum[w] = incl;
    __syncthreads();
    if (t == 0) {
        int run = 0;
        #pragma unroll
        for (int i = 0; i < 4; ++i) { int x = wsum[i]; wsum[i] = run; run += x; }
        bsums[b] = run;   // block total
    }
    __syncthreads();
    int base = wsum[w] + incl - s;   // exclusive prefix of this thread's chunk
    if (i0 + 0 < N_NODES) excl[i0 + 0] = base;
    if (i0 + 1 < N_NODES) excl[i0 + 1] = base + v0;
    if (i0 + 2 < N_NODES) excl[i0 + 2] = base + v0 + v1;
    if (i0 + 3 < N_NODES) excl[i0 + 3] = base + v0 + v1 + v2;
}

__global__ void k_scan_mid(int* __restrict__ bsums) {
    int t = threadIdx.x;  // 64 threads, SCAN_BLOCKS <= 64
    int v = (t < SCAN_BLOCKS) ? bsums[t] : 0;
    int incl = v;
    #pragma unroll
    for (int d = 1; d < 64; d <<= 1) {
        int u = __shfl_up(incl, d);
        if (t >= d) incl += u;
    }
    if (t < SCAN_BLOCKS) bsums[t] = incl - v;  // exclusive
}

__global__ void k_scan_add(int* __restrict__ row_ptr, const int* __restrict__ bsums) {
    int b = blockIdx.x, t = threadIdx.x;
    int off = bsums[b];
    int i0 = b * 1024 + t * 4;
    #pragma unroll
    for (int j = 0; j < 4; ++j)
        if (i0 + j < N_NODES) row_ptr[i0 + j] += off;
    if (b == 0 && t == 0) row_ptr[N_NODES] = EP;
}

__global__ void k_scatter(const int* __restrict__ ei, const int* __restrict__ row_ptr,
                          int* __restrict__ fill, int* __restrict__ colb) {
    int e = blockIdx.x * 256 + threadIdx.x;
    if (e >= EP) return;
    int s, d;
    if (e < N_EDGES) { s = ei[e]; d = ei[N_EDGES + e]; }
    else             { s = e - N_EDGES; d = s; }
    int pos = row_ptr[d] + atomicAdd(&fill[d], 1);
    colb[pos] = s;
}

// ---------------- Layer 1 GEMM + fused attention logits ----------------
// xp1 emitted in bf16 (gather mirror for k_agg1, halves gather bytes);
// alpha_src/alpha_dst computed in epilogue from fp32 accumulators (8-lane
// shuffle reduce per head). Block = 32 rows x 256 cols, 256 threads.
// Wave w owns rows w*8..w*8+7; lane l owns cols 4l..4l+3.
#define G1_ROWS 32
#define G1_GRID 1563            // ceil(50000/32); last block has 16 valid rows
__global__ void k_gemm1(const float* __restrict__ x, const float* __restrict__ W1,
                        const float* __restrict__ asrc, const float* __restrict__ adst,
                        ushort4* __restrict__ xp1b,
                        float* __restrict__ as1, float* __restrict__ ad1) {
    __shared__ float xs[G1_ROWS * 256];
    int t = threadIdx.x;
    int row0 = blockIdx.x * G1_ROWS;

    // stage A-tile: 32x256 floats = 2048 float4, 8 per thread, linear copy
    const float4* x4 = (const float4*)x;
    float4* xs4w = (float4*)xs;
    #pragma unroll
    for (int c = 0; c < 8; ++c) {
        int idx = c * 256 + t;            // float4 index within tile
        int r = idx >> 6, c4 = idx & 63;
        int gr = row0 + r;
        if (gr > N_NODES - 1) gr = N_NODES - 1;   // clamp (results unused)
        xs4w[idx] = x4[gr * 64 + c4];
    }
    __syncthreads();

    int l = t & 63, w = t >> 6;
    int r0 = w * 8;                       // this wave's first row in tile
    const float4* xs4 = (const float4*)xs;
    const float4* W4 = (const float4*)W1; // W1[k][c]: float4 index k*64 + (c/4)

    float4 acc[8];
    #pragma unroll
    for (int r = 0; r < 8; ++r) acc[r] = make_float4(0.f, 0.f, 0.f, 0.f);

    #pragma unroll 4
    for (int k4 = 0; k4 < 64; ++k4) {
        float4 wv0 = W4[(k4 * 4 + 0) * 64 + l];
        float4 wv1 = W4[(k4 * 4 + 1) * 64 + l];
        float4 wv2 = W4[(k4 * 4 + 2) * 64 + l];
        float4 wv3 = W4[(k4 * 4 + 3) * 64 + l];
        #pragma unroll
        for (int r = 0; r < 8; ++r) {
            float4 av = xs4[(r0 + r) * 64 + k4];   // wave-uniform broadcast
            acc[r].x = fmaf(av.x, wv0.x, acc[r].x);
            acc[r].x = fmaf(av.y, wv1.x, acc[r].x);
            acc[r].x = fmaf(av.z, wv2.x, acc[r].x);
            acc[r].x = fmaf(av.w, wv3.x, acc[r].x);
            acc[r].y = fmaf(av.x, wv0.y, acc[r].y);
            acc[r].y = fmaf(av.y, wv1.y, acc[r].y);
            acc[r].y = fmaf(av.z, wv2.y, acc[r].y);
            acc[r].y = fmaf(av.w, wv3.y, acc[r].y);
            acc[r].z = fmaf(av.x, wv0.z, acc[r].z);
            acc[r].z = fmaf(av.y, wv1.z, acc[r].z);
            acc[r].z = fmaf(av.z, wv2.z, acc[r].z);
            acc[r].z = fmaf(av.w, wv3.z, acc[r].z);
            acc[r].w = fmaf(av.x, wv0.w, acc[r].w);
            acc[r].w = fmaf(av.y, wv1.w, acc[r].w);
            acc[r].w = fmaf(av.z, wv2.w, acc[r].w);
            acc[r].w = fmaf(av.w, wv3.w, acc[r].w);
        }
    }

    // epilogue: bf16 store + fused attention logits
    float4 a_s = ((const float4*)asrc)[l];    // asrc[h][c] flat: cols 4l..4l+3
    float4 a_d = ((const float4*)adst)[l];
    #pragma unroll
    for (int r = 0; r < 8; ++r) {
        int gr = row0 + r0 + r;
        float4 v = acc[r];
        float ps = v.x * a_s.x + v.y * a_s.y + v.z * a_s.z + v.w * a_s.w;
        float pd = v.x * a_d.x + v.y * a_d.y + v.z * a_d.z + v.w * a_d.w;
        #pragma unroll
        for (int m = 1; m < 8; m <<= 1) {
            ps += __shfl_xor(ps, m);
            pd += __shfl_xor(pd, m);
        }
        if (gr < N_NODES) {
            ushort4 o;
            o.x = bf16_rn(v.x); o.y = bf16_rn(v.y);
            o.z = bf16_rn(v.z); o.w = bf16_rn(v.w);
            xp1b[gr * 64 + l] = o;
            if ((l & 7) == 0) {
                int h = l >> 3;
                as1[gr * 8 + h] = ps;
                ad1[gr * 8 + h] = pd;
            }
        }
    }
}

// ---------------- fused segment-softmax + aggregate, layer 1 ----------------
// softmax aggregation = (sum p_i * x_i) / (sum p_i); no max-subtraction needed
// (|e| small, fp32 exp safe). One wave per node; bf16 gather (512 B/edge/wave).
// Manual 4-edge unroll: 4 independent gathers in flight to hide L2/L3 latency.
__global__ void k_agg1(const ushort4* __restrict__ xpb, const float* __restrict__ as1,
                       const float* __restrict__ ad1, const int* __restrict__ row_ptr,
                       const int* __restrict__ colb, const float* __restrict__ b1,
                       float* __restrict__ hout) {
    int t = threadIdx.x, l = t & 63, w = t >> 6;
    int n = blockIdx.x * 4 + w;
    int hidx = l >> 3;
    float adn = ad1[n * 8 + hidx];
    int start = row_ptr[n], end = row_ptr[n + 1];
    float4 acc = {0.f, 0.f, 0.f, 0.f};
    float den = 0.f;
    int j = start;
    for (; j + 4 <= end; j += 4) {
        int s0 = colb[j], s1 = colb[j + 1], s2 = colb[j + 2], s3 = colb[j + 3];
        ushort4 x0 = xpb[s0 * 64 + l];
        ushort4 x1 = xpb[s1 * 64 + l];
        ushort4 x2 = xpb[s2 * 64 + l];
        ushort4 x3 = xpb[s3 * 64 + l];
        float e0 = as1[s0 * 8 + hidx] + adn;
        float e1 = as1[s1 * 8 + hidx] + adn;
        float e2 = as1[s2 * 8 + hidx] + adn;
        float e3 = as1[s3 * 8 + hidx] + adn;
        e0 = (e0 > 0.f) ? e0 : NEG * e0;
        e1 = (e1 > 0.f) ? e1 : NEG * e1;
        e2 = (e2 > 0.f) ? e2 : NEG * e2;
        e3 = (e3 > 0.f) ? e3 : NEG * e3;
        float p0 = __expf(e0), p1 = __expf(e1), p2 = __expf(e2), p3 = __expf(e3);
        den += (p0 + p1) + (p2 + p3);
        acc.x = fmaf(p0, bf16_tof(x0.x), acc.x);
        acc.y = fmaf(p0, bf16_tof(x0.y), acc.y);
        acc.z = fmaf(p0, bf16_tof(x0.z), acc.z);
        acc.w = fmaf(p0, bf16_tof(x0.w), acc.w);
        acc.x = fmaf(p1, bf16_tof(x1.x), acc.x);
        acc.y = fmaf(p1, bf16_tof(x1.y), acc.y);
        acc.z = fmaf(p1, bf16_tof(x1.z), acc.z);
        acc.w = fmaf(p1, bf16_tof(x1.w), acc.w);
        acc.x = fmaf(p2, bf16_tof(x2.x), acc.x);
        acc.y = fmaf(p2, bf16_tof(x2.y), acc.y);
        acc.z = fmaf(p2, bf16_tof(x2.z), acc.z);
        acc.w = fmaf(p2, bf16_tof(x2.w), acc.w);
        acc.x = fmaf(p3, bf16_tof(x3.x), acc.x);
        acc.y = fmaf(p3, bf16_tof(x3.y), acc.y);
        acc.z = fmaf(p3, bf16_tof(x3.z), acc.z);
        acc.w = fmaf(p3, bf16_tof(x3.w), acc.w);
    }
    for (; j < end; ++j) {
        int s = colb[j];
        ushort4 xv = xpb[s * 64 + l];
        float e = as1[s * 8 + hidx] + adn;
        e = (e > 0.f) ? e : NEG * e;
        float p = __expf(e);
        den += p;
        acc.x = fmaf(p, bf16_tof(xv.x), acc.x);
        acc.y = fmaf(p, bf16_tof(xv.y), acc.y);
        acc.z = fmaf(p, bf16_tof(xv.z), acc.z);
        acc.w = fmaf(p, bf16_tof(xv.w), acc.w);
    }
    float4 bv = ((const float4*)b1)[l];
    float inv = 1.f / den;
    float4 o;
    o.x = fmaxf(acc.x * inv + bv.x, 0.f);
    o.y = fmaxf(acc.y * inv + bv.y, 0.f);
    o.z = fmaxf(acc.z * inv + bv.z, 0.f);
    o.w = fmaxf(acc.w * inv + bv.w, 0.f);
    ((float4*)hout)[n * 64 + l] = o;
}

// ---------------- layer 2 projection + logits: xp2 = h @ W2 (256->2) ----------------
// wave per node; W2 row-major (256,2): lane l needs W2[8l..8l+7]
__global__ void k_proj2(const float* __restrict__ h, const float* __restrict__ W2,
                        const float* __restrict__ as2w, const float* __restrict__ ad2w,
                        float* __restrict__ xp2, float* __restrict__ as2,
                        float* __restrict__ ad2) {
    int t = threadIdx.x, l = t & 63, w = t >> 6;
    int n = blockIdx.x * 4 + w;
    float4 hv = ((const float4*)h)[n * 64 + l];
    float4 wa = ((const float4*)W2)[2 * l];
    float4 wb = ((const float4*)W2)[2 * l + 1];
    float d0 = hv.x * wa.x + hv.y * wa.z + hv.z * wb.x + hv.w * wb.z;
    float d1 = hv.x * wa.y + hv.y * wa.w + hv.z * wb.y + hv.w * wb.w;
    #pragma unroll
    for (int m = 1; m < 64; m <<= 1) {
        d0 += __shfl_xor(d0, m);
        d1 += __shfl_xor(d1, m);
    }
    if (l == 0) {
        xp2[2 * n] = d0;
        xp2[2 * n + 1] = d1;
        as2[n] = d0 * as2w[0] + d1 * as2w[1];
        ad2[n] = d0 * ad2w[0] + d1 * ad2w[1];
    }
}

// ---------------- fused segment-softmax + aggregate, layer 2 (2 channels) ----------------
// wave per node, lanes parallel over incident edges
__global__ void k_agg2(const float* __restrict__ xp2, const float* __restrict__ as2,
                       const float* __restrict__ ad2, const int* __restrict__ row_ptr,
                       const int* __restrict__ colb, const float* __restrict__ b2,
                       float* __restrict__ out) {
    int t = threadIdx.x, l = t & 63, w = t >> 6;
    int n = blockIdx.x * 4 + w;
    int start = row_ptr[n], end = row_ptr[n + 1];
    float adn = ad2[n];
    float a0 = 0.f, a1 = 0.f, den = 0.f;
    for (int j = start + l; j < end; j += 64) {
        int s = colb[j];
        float e = as2[s] + adn;
        e = (e > 0.f) ? e : NEG * e;
        float p = __expf(e);
        den += p;
        a0 = fmaf(p, xp2[2 * s], a0);
        a1 = fmaf(p, xp2[2 * s + 1], a1);
    }
    #pragma unroll
    for (int m = 1; m < 64; m <<= 1) {
        a0 += __shfl_xor(a0, m);
        a1 += __shfl_xor(a1, m);
        den += __shfl_xor(den, m);
    }
    if (l == 0) {
        out[2 * n] = a0 / den + b2[0];
        out[2 * n + 1] = a1 / den + b2[1];
    }
}

extern "C" void kernel_launch(void* const* d_in, const int* in_sizes, int n_in,
                              void* d_out, int out_size, void* d_ws, size_t ws_size,
                              hipStream_t stream) {
    const float* x     = (const float*)d_in[0];
    const int*   ei    = (const int*)d_in[1];
    const float* W1    = (const float*)d_in[2];
    const float* asrc1 = (const float*)d_in[3];
    const float* adst1 = (const float*)d_in[4];
    const float* b1    = (const float*)d_in[5];
    const float* W2    = (const float*)d_in[6];
    const float* asrc2 = (const float*)d_in[7];
    const float* adst2 = (const float*)d_in[8];
    const float* b2    = (const float*)d_in[9];
    float* out = (float*)d_out;

    char* ws = (char*)d_ws;
    ushort4* xp1b  = (ushort4*)(ws + 0);            // 25,600,000 B (bf16 mirror)
    float* hbuf    = (float*)(ws + 51200000);       // 51,200,000 B
    float* as1     = (float*)(ws + 102400000);      //  1,600,000 B
    float* ad1     = (float*)(ws + 104000000);      //  1,600,000 B
    float* xp2     = (float*)(ws + 105600000);      //    400,000 B
    float* as2     = (float*)(ws + 106000000);      //    200,000 B
    float* ad2     = (float*)(ws + 106200000);      //    200,000 B
    int*   counts  = (int*)  (ws + 106400000);      //    200,000 B
    int*   fill    = (int*)  (ws + 106600000);      //    200,000 B (contig w/ counts)
    int*   row_ptr = (int*)  (ws + 106800000);      //    200,064 B
    int*   colb    = (int*)  (ws + 107000064);      //  3,400,000 B
    int*   bsums   = (int*)  (ws + 110400064);      //        256 B

    // zero counts + fill in one memset (contiguous)
    hipMemsetAsync(counts, 0, 400000, stream);

    int egrid = (EP + 255) / 256;
    k_hist      <<<egrid,       256, 0, stream>>>(ei, counts);
    k_scan_block<<<SCAN_BLOCKS, 256, 0, stream>>>(counts, row_ptr, bsums);
    k_scan_mid  <<<1,            64, 0, stream>>>(bsums);
    k_scan_add  <<<SCAN_BLOCKS, 256, 0, stream>>>(row_ptr, bsums);
    k_scatter   <<<egrid,       256, 0, stream>>>(ei, row_ptr, fill, colb);

    k_gemm1     <<<G1_GRID, 256, 0, stream>>>(x, W1, asrc1, adst1, xp1b, as1, ad1);
    k_agg1      <<<12500,  256, 0, stream>>>(xp1b, as1, ad1, row_ptr, colb, b1, hbuf);
    k_proj2     <<<12500,  256, 0, stream>>>(hbuf, W2, asrc2, adst2, xp2, as2, ad2);
    k_agg2      <<<12500,  256, 0, stream>>>(xp2, as2, ad2, row_ptr, colb, b2, out);
}

// Round 4
// 322.573 us; speedup vs baseline: 1.4569x; 1.1343x over previous
//
#include <hip/hip_runtime.h>
#include <math.h>

#define N_NODES 50000
#define N_EDGES 800000
#define EP (N_EDGES + N_NODES)   // 850000 edges incl. self loops
#define NEG 0.2f
#define SCAN_BLOCKS 49           // ceil(50000/1024)

typedef __attribute__((ext_vector_type(8))) short bf16x8;
typedef __attribute__((ext_vector_type(4))) float f32x4;

// bf16 round-to-nearest-even from fp32
static __device__ __forceinline__ unsigned short bf16_rn(float f) {
    union { float f; unsigned int u; } v; v.f = f;
    unsigned int u = v.u;
    unsigned int r = (u + 0x7FFFu + ((u >> 16) & 1u)) >> 16;
    return (unsigned short)r;
}
static __device__ __forceinline__ float bf16_tof(unsigned short u) {
    union { unsigned int u; float f; } v; v.u = ((unsigned int)u) << 16;
    return v.f;
}

// ---------------- CSR build ----------------

__global__ void k_hist(const int* __restrict__ ei, int* __restrict__ counts) {
    int e = blockIdx.x * 256 + threadIdx.x;
    if (e >= EP) return;
    int d = (e < N_EDGES) ? ei[N_EDGES + e] : (e - N_EDGES);
    atomicAdd(&counts[d], 1);
}

__global__ void k_scan_block(const int* __restrict__ counts, int* __restrict__ excl,
                             int* __restrict__ bsums) {
    __shared__ int wsum[4];
    int b = blockIdx.x, t = threadIdx.x;
    int lane = t & 63, w = t >> 6;
    int i0 = b * 1024 + t * 4;
    int v0 = (i0 + 0 < N_NODES) ? counts[i0 + 0] : 0;
    int v1 = (i0 + 1 < N_NODES) ? counts[i0 + 1] : 0;
    int v2 = (i0 + 2 < N_NODES) ? counts[i0 + 2] : 0;
    int v3 = (i0 + 3 < N_NODES) ? counts[i0 + 3] : 0;
    int s = v0 + v1 + v2 + v3;
    int incl = s;
    #pragma unroll
    for (int d = 1; d < 64; d <<= 1) {
        int u = __shfl_up(incl, d);
        if (lane >= d) incl += u;
    }
    if (lane == 63) wsum[w] = incl;
    __syncthreads();
    if (t == 0) {
        int run = 0;
        #pragma unroll
        for (int i = 0; i < 4; ++i) { int x = wsum[i]; wsum[i] = run; run += x; }
        bsums[b] = run;   // block total
    }
    __syncthreads();
    int base = wsum[w] + incl - s;   // exclusive prefix of this thread's chunk
    if (i0 + 0 < N_NODES) excl[i0 + 0] = base;
    if (i0 + 1 < N_NODES) excl[i0 + 1] = base + v0;
    if (i0 + 2 < N_NODES) excl[i0 + 2] = base + v0 + v1;
    if (i0 + 3 < N_NODES) excl[i0 + 3] = base + v0 + v1 + v2;
}

__global__ void k_scan_mid(int* __restrict__ bsums) {
    int t = threadIdx.x;  // 64 threads, SCAN_BLOCKS <= 64
    int v = (t < SCAN_BLOCKS) ? bsums[t] : 0;
    int incl = v;
    #pragma unroll
    for (int d = 1; d < 64; d <<= 1) {
        int u = __shfl_up(incl, d);
        if (t >= d) incl += u;
    }
    if (t < SCAN_BLOCKS) bsums[t] = incl - v;  // exclusive
}

__global__ void k_scan_add(int* __restrict__ row_ptr, const int* __restrict__ bsums) {
    int b = blockIdx.x, t = threadIdx.x;
    int off = bsums[b];
    int i0 = b * 1024 + t * 4;
    #pragma unroll
    for (int j = 0; j < 4; ++j)
        if (i0 + j < N_NODES) row_ptr[i0 + j] += off;
    if (b == 0 && t == 0) row_ptr[N_NODES] = EP;
}

__global__ void k_scatter(const int* __restrict__ ei, const int* __restrict__ row_ptr,
                          int* __restrict__ fill, int* __restrict__ colb) {
    int e = blockIdx.x * 256 + threadIdx.x;
    if (e >= EP) return;
    int s, d;
    if (e < N_EDGES) { s = ei[e]; d = ei[N_EDGES + e]; }
    else             { s = e - N_EDGES; d = s; }
    int pos = row_ptr[d] + atomicAdd(&fill[d], 1);
    colb[pos] = s;
}

// ---------------- W1 transpose + bf16 convert: Wt[c][k] = W1[k][c] ----------------
__global__ void k_cvtW(const float* __restrict__ W1, unsigned short* __restrict__ Wt) {
    int c = blockIdx.x;   // 256
    int k = threadIdx.x;  // 256
    Wt[c * 256 + k] = bf16_rn(W1[k * 256 + c]);
}

// ---------------- Layer 1 GEMM via bf16 MFMA ----------------
// xp1b[50000][256] bf16 = (x @ W1), fp32 accumulate.
// Block = 64 rows x 256 cols, 256 threads (4 waves); wave w owns rows
// rowbase+w*16 .. +15, all 16 col-tiles of 16. K chunked by 32
// (one mfma_f32_16x16x32_bf16 k-step per chunk per tile).
// LDS holds A/B fragments PRE-SHUFFLED in exact lane order so all LDS
// traffic is lane-linear b128 (conflict-free):
//   A frag lane l of wave w: A[m=l&15][k=(l>>4)*8+j]   (verified layout, m120)
//   B frag lane l, tile nt:  B[k=(l>>4)*8+j][n=nt*16+(l&15)]  (= Wt[n][k..k+8])
//   C/D lane l, reg r: row=(l>>4)*4+r, col=l&15        (verified layout, m89/m91)
#define GM_GRID 782   // ceil(50000/64)
__global__ void k_gemm1m(const float* __restrict__ x, const unsigned short* __restrict__ Wt,
                         unsigned short* __restrict__ xp1b) {
    __shared__ bf16x8 lds[4 * 64 + 16 * 64];   // A frags (4 waves) + B frags (16 tiles); 20 KB
    int t = threadIdx.x, l = t & 63, w = t >> 6;
    int rowbase = blockIdx.x * 64 + w * 16;
    int m = l & 15, kg = l >> 4;

    f32x4 acc[16];
    #pragma unroll
    for (int nt = 0; nt < 16; ++nt) acc[nt] = (f32x4){0.f, 0.f, 0.f, 0.f};

    int gra = rowbase + m;                   // A staging source row (clamped)
    if (gra > N_NODES - 1) gra = N_NODES - 1;
    const float4* x4 = (const float4*)x;
    const bf16x8* WtV = (const bf16x8*)Wt;

    for (int c = 0; c < 8; ++c) {
        int k0 = c * 32;
        __syncthreads();   // protect LDS reuse across chunks
        // stage this thread's A frag-lane: 8 fp32 -> 8 bf16
        {
            int fi = (gra * 256 + k0 + kg * 8) >> 2;   // float4 index
            float4 xa = x4[fi];
            float4 xb = x4[fi + 1];
            bf16x8 af;
            af[0] = (short)bf16_rn(xa.x); af[1] = (short)bf16_rn(xa.y);
            af[2] = (short)bf16_rn(xa.z); af[3] = (short)bf16_rn(xa.w);
            af[4] = (short)bf16_rn(xb.x); af[5] = (short)bf16_rn(xb.y);
            af[6] = (short)bf16_rn(xb.z); af[7] = (short)bf16_rn(xb.w);
            lds[w * 64 + l] = af;
        }
        // stage B frags: 1024 frag-lanes, 4 per thread, straight 16B copies
        #pragma unroll
        for (int q = 0; q < 4; ++q) {
            int f = t * 4 + q;
            int nt = f >> 6, fl = f & 63;
            int n = nt * 16 + (fl & 15), fkg = fl >> 4;
            lds[256 + f] = WtV[n * 32 + (k0 >> 3) + fkg];
        }
        __syncthreads();
        bf16x8 aF = lds[w * 64 + l];
        #pragma unroll
        for (int nt = 0; nt < 16; ++nt)
            acc[nt] = __builtin_amdgcn_mfma_f32_16x16x32_bf16(
                aF, lds[256 + nt * 64 + l], acc[nt], 0, 0, 0);
    }

    // epilogue: bf16 store, C-layout row=(l>>4)*4+reg, col=nt*16+(l&15)
    int cbase = l & 15, rq = l >> 4;
    #pragma unroll
    for (int reg = 0; reg < 4; ++reg) {
        int gr = rowbase + rq * 4 + reg;
        if (gr < N_NODES) {
            #pragma unroll
            for (int nt = 0; nt < 16; ++nt)
                xp1b[gr * 256 + nt * 16 + cbase] = bf16_rn(acc[nt][reg]);
        }
    }
}

// ---------------- per-node attention logits, layer 1 (bf16 read) ----------------
__global__ void k_alphas1(const ushort4* __restrict__ xpb, const float* __restrict__ asrc,
                          const float* __restrict__ adst,
                          float* __restrict__ as1, float* __restrict__ ad1) {
    int t = threadIdx.x, l = t & 63, w = t >> 6;
    int n = blockIdx.x * 4 + w;
    ushort4 xq = xpb[n * 64 + l];
    float x0 = bf16_tof(xq.x), x1 = bf16_tof(xq.y), x2 = bf16_tof(xq.z), x3 = bf16_tof(xq.w);
    float4 a_s = ((const float4*)asrc)[l];
    float4 a_d = ((const float4*)adst)[l];
    float ds = x0 * a_s.x + x1 * a_s.y + x2 * a_s.z + x3 * a_s.w;
    float dd = x0 * a_d.x + x1 * a_d.y + x2 * a_d.z + x3 * a_d.w;
    #pragma unroll
    for (int m = 1; m < 8; m <<= 1) {
        ds += __shfl_xor(ds, m);
        dd += __shfl_xor(dd, m);
    }
    if ((l & 7) == 0) {
        int h = l >> 3;
        as1[n * 8 + h] = ds;
        ad1[n * 8 + h] = dd;
    }
}

// ---------------- fused segment-softmax + aggregate, layer 1 ----------------
__global__ void k_agg1(const ushort4* __restrict__ xpb, const float* __restrict__ as1,
                       const float* __restrict__ ad1, const int* __restrict__ row_ptr,
                       const int* __restrict__ colb, const float* __restrict__ b1,
                       float* __restrict__ hout) {
    int t = threadIdx.x, l = t & 63, w = t >> 6;
    int n = blockIdx.x * 4 + w;
    int hidx = l >> 3;
    float adn = ad1[n * 8 + hidx];
    int start = row_ptr[n], end = row_ptr[n + 1];
    float4 acc = {0.f, 0.f, 0.f, 0.f};
    float den = 0.f;
    int j = start;
    for (; j + 4 <= end; j += 4) {
        int s0 = colb[j], s1 = colb[j + 1], s2 = colb[j + 2], s3 = colb[j + 3];
        ushort4 x0 = xpb[s0 * 64 + l];
        ushort4 x1 = xpb[s1 * 64 + l];
        ushort4 x2 = xpb[s2 * 64 + l];
        ushort4 x3 = xpb[s3 * 64 + l];
        float e0 = as1[s0 * 8 + hidx] + adn;
        float e1 = as1[s1 * 8 + hidx] + adn;
        float e2 = as1[s2 * 8 + hidx] + adn;
        float e3 = as1[s3 * 8 + hidx] + adn;
        e0 = (e0 > 0.f) ? e0 : NEG * e0;
        e1 = (e1 > 0.f) ? e1 : NEG * e1;
        e2 = (e2 > 0.f) ? e2 : NEG * e2;
        e3 = (e3 > 0.f) ? e3 : NEG * e3;
        float p0 = __expf(e0), p1 = __expf(e1), p2 = __expf(e2), p3 = __expf(e3);
        den += (p0 + p1) + (p2 + p3);
        acc.x = fmaf(p0, bf16_tof(x0.x), acc.x);
        acc.y = fmaf(p0, bf16_tof(x0.y), acc.y);
        acc.z = fmaf(p0, bf16_tof(x0.z), acc.z);
        acc.w = fmaf(p0, bf16_tof(x0.w), acc.w);
        acc.x = fmaf(p1, bf16_tof(x1.x), acc.x);
        acc.y = fmaf(p1, bf16_tof(x1.y), acc.y);
        acc.z = fmaf(p1, bf16_tof(x1.z), acc.z);
        acc.w = fmaf(p1, bf16_tof(x1.w), acc.w);
        acc.x = fmaf(p2, bf16_tof(x2.x), acc.x);
        acc.y = fmaf(p2, bf16_tof(x2.y), acc.y);
        acc.z = fmaf(p2, bf16_tof(x2.z), acc.z);
        acc.w = fmaf(p2, bf16_tof(x2.w), acc.w);
        acc.x = fmaf(p3, bf16_tof(x3.x), acc.x);
        acc.y = fmaf(p3, bf16_tof(x3.y), acc.y);
        acc.z = fmaf(p3, bf16_tof(x3.z), acc.z);
        acc.w = fmaf(p3, bf16_tof(x3.w), acc.w);
    }
    for (; j < end; ++j) {
        int s = colb[j];
        ushort4 xv = xpb[s * 64 + l];
        float e = as1[s * 8 + hidx] + adn;
        e = (e > 0.f) ? e : NEG * e;
        float p = __expf(e);
        den += p;
        acc.x = fmaf(p, bf16_tof(xv.x), acc.x);
        acc.y = fmaf(p, bf16_tof(xv.y), acc.y);
        acc.z = fmaf(p, bf16_tof(xv.z), acc.z);
        acc.w = fmaf(p, bf16_tof(xv.w), acc.w);
    }
    float4 bv = ((const float4*)b1)[l];
    float inv = 1.f / den;
    float4 o;
    o.x = fmaxf(acc.x * inv + bv.x, 0.f);
    o.y = fmaxf(acc.y * inv + bv.y, 0.f);
    o.z = fmaxf(acc.z * inv + bv.z, 0.f);
    o.w = fmaxf(acc.w * inv + bv.w, 0.f);
    ((float4*)hout)[n * 64 + l] = o;
}

// ---------------- layer 2 projection + logits: xp2 = h @ W2 (256->2) ----------------
__global__ void k_proj2(const float* __restrict__ h, const float* __restrict__ W2,
                        const float* __restrict__ as2w, const float* __restrict__ ad2w,
                        float* __restrict__ xp2, float* __restrict__ as2,
                        float* __restrict__ ad2) {
    int t = threadIdx.x, l = t & 63, w = t >> 6;
    int n = blockIdx.x * 4 + w;
    float4 hv = ((const float4*)h)[n * 64 + l];
    float4 wa = ((const float4*)W2)[2 * l];
    float4 wb = ((const float4*)W2)[2 * l + 1];
    float d0 = hv.x * wa.x + hv.y * wa.z + hv.z * wb.x + hv.w * wb.z;
    float d1 = hv.x * wa.y + hv.y * wa.w + hv.z * wb.y + hv.w * wb.w;
    #pragma unroll
    for (int m = 1; m < 64; m <<= 1) {
        d0 += __shfl_xor(d0, m);
        d1 += __shfl_xor(d1, m);
    }
    if (l == 0) {
        xp2[2 * n] = d0;
        xp2[2 * n + 1] = d1;
        as2[n] = d0 * as2w[0] + d1 * as2w[1];
        ad2[n] = d0 * ad2w[0] + d1 * ad2w[1];
    }
}

// ---------------- fused segment-softmax + aggregate, layer 2 (2 channels) ----------------
__global__ void k_agg2(const float* __restrict__ xp2, const float* __restrict__ as2,
                       const float* __restrict__ ad2, const int* __restrict__ row_ptr,
                       const int* __restrict__ colb, const float* __restrict__ b2,
                       float* __restrict__ out) {
    int t = threadIdx.x, l = t & 63, w = t >> 6;
    int n = blockIdx.x * 4 + w;
    int start = row_ptr[n], end = row_ptr[n + 1];
    float adn = ad2[n];
    float a0 = 0.f, a1 = 0.f, den = 0.f;
    for (int j = start + l; j < end; j += 64) {
        int s = colb[j];
        float e = as2[s] + adn;
        e = (e > 0.f) ? e : NEG * e;
        float p = __expf(e);
        den += p;
        a0 = fmaf(p, xp2[2 * s], a0);
        a1 = fmaf(p, xp2[2 * s + 1], a1);
    }
    #pragma unroll
    for (int m = 1; m < 64; m <<= 1) {
        a0 += __shfl_xor(a0, m);
        a1 += __shfl_xor(a1, m);
        den += __shfl_xor(den, m);
    }
    if (l == 0) {
        out[2 * n] = a0 / den + b2[0];
        out[2 * n + 1] = a1 / den + b2[1];
    }
}

extern "C" void kernel_launch(void* const* d_in, const int* in_sizes, int n_in,
                              void* d_out, int out_size, void* d_ws, size_t ws_size,
                              hipStream_t stream) {
    const float* x     = (const float*)d_in[0];
    const int*   ei    = (const int*)d_in[1];
    const float* W1    = (const float*)d_in[2];
    const float* asrc1 = (const float*)d_in[3];
    const float* adst1 = (const float*)d_in[4];
    const float* b1    = (const float*)d_in[5];
    const float* W2    = (const float*)d_in[6];
    const float* asrc2 = (const float*)d_in[7];
    const float* adst2 = (const float*)d_in[8];
    const float* b2    = (const float*)d_in[9];
    float* out = (float*)d_out;

    char* ws = (char*)d_ws;
    unsigned short* xp1b = (unsigned short*)(ws + 0);   // 25,600,000 B (bf16)
    unsigned short* Wt   = (unsigned short*)(ws + 25600000); // 131,072 B (bf16 W1^T)
    float* hbuf    = (float*)(ws + 51200000);       // 51,200,000 B
    float* as1     = (float*)(ws + 102400000);      //  1,600,000 B
    float* ad1     = (float*)(ws + 104000000);      //  1,600,000 B
    float* xp2     = (float*)(ws + 105600000);      //    400,000 B
    float* as2     = (float*)(ws + 106000000);      //    200,000 B
    float* ad2     = (float*)(ws + 106200000);      //    200,000 B
    int*   counts  = (int*)  (ws + 106400000);      //    200,000 B
    int*   fill    = (int*)  (ws + 106600000);      //    200,000 B (contig w/ counts)
    int*   row_ptr = (int*)  (ws + 106800000);      //    200,064 B
    int*   colb    = (int*)  (ws + 107000064);      //  3,400,000 B
    int*   bsums   = (int*)  (ws + 110400064);      //        256 B

    hipMemsetAsync(counts, 0, 400000, stream);      // counts + fill

    int egrid = (EP + 255) / 256;
    k_hist      <<<egrid,       256, 0, stream>>>(ei, counts);
    k_scan_block<<<SCAN_BLOCKS, 256, 0, stream>>>(counts, row_ptr, bsums);
    k_scan_mid  <<<1,            64, 0, stream>>>(bsums);
    k_scan_add  <<<SCAN_BLOCKS, 256, 0, stream>>>(row_ptr, bsums);
    k_scatter   <<<egrid,       256, 0, stream>>>(ei, row_ptr, fill, colb);

    k_cvtW      <<<256,    256, 0, stream>>>(W1, Wt);
    k_gemm1m    <<<GM_GRID, 256, 0, stream>>>(x, Wt, xp1b);
    k_alphas1   <<<12500,  256, 0, stream>>>((const ushort4*)xp1b, asrc1, adst1, as1, ad1);
    k_agg1      <<<12500,  256, 0, stream>>>((const ushort4*)xp1b, as1, ad1, row_ptr, colb, b1, hbuf);
    k_proj2     <<<12500,  256, 0, stream>>>(hbuf, W2, asrc2, adst2, xp2, as2, ad2);
    k_agg2      <<<12500,  256, 0, stream>>>(xp2, as2, ad2, row_ptr, colb, b2, out);
}